// Round 7
// baseline (804.078 us; speedup 1.0000x reference)
//
#include <hip/hip_runtime.h>

#define TT 1500
#define BB 96
#define VV 128
#define LGT 256
#define LCAP 512
#define NEGF (-1.0e30f)
#define L2E 1.4426950408889634f
#define LN2F 0.6931471805599453f
#define HREF 30  // refresh cadence: 2*HREF=60 < 63-state ghost

// ---------------------------------------------------------------------------
// Kernel 1: greedy decode (unchanged).
// ---------------------------------------------------------------------------
__global__ __launch_bounds__(256) void decode_kernel(
    const float* __restrict__ acts, const int* __restrict__ act_lens,
    int* __restrict__ dec, int* __restrict__ dec_lens) {
  __shared__ int preds[TT];
  __shared__ int sc[256];
  const int b = blockIdx.x;
  const int tid = threadIdx.x;
  const int Tl = act_lens[b];
  for (int t = tid; t < Tl; t += 256) {
    const float4* r4 = (const float4*)(acts + ((size_t)t * BB + b) * VV);
    float best = -3.4e38f;
    int bi = 0;
#pragma unroll
    for (int i = 0; i < VV / 4; i++) {
      float4 v = r4[i];
      if (v.x > best) { best = v.x; bi = 4 * i; }
      if (v.y > best) { best = v.y; bi = 4 * i + 1; }
      if (v.z > best) { best = v.z; bi = 4 * i + 2; }
      if (v.w > best) { best = v.w; bi = 4 * i + 3; }
    }
    preds[t] = bi;
  }
  __syncthreads();

  int pv[6];
  bool fl[6];
  int cnt = 0;
#pragma unroll
  for (int j = 0; j < 6; j++) {
    int t = tid * 6 + j;
    bool valid = t < Tl;
    int p = valid ? preds[t] : 0;
    int pr = (t == 0) ? -1 : (valid ? preds[t - 1] : -1);
    bool f = valid && (p != 0) && (p != pr);
    pv[j] = p;
    fl[j] = f;
    cnt += f;
  }
  sc[tid] = cnt;
  __syncthreads();
  for (int off = 1; off < 256; off <<= 1) {
    int v = sc[tid];
    if (tid >= off) v += sc[tid - off];
    __syncthreads();
    sc[tid] = v;
    __syncthreads();
  }
  int pos = sc[tid] - cnt;  // exclusive prefix
  int total = sc[255];
  int* db = dec + (size_t)b * LCAP;
#pragma unroll
  for (int j = 0; j < 6; j++) {
    if (fl[j]) {
      if (pos < LCAP) db[pos] = pv[j];
      pos++;
    }
  }
  if (tid == 0) {
    if (total == 0) db[0] = 0;
    dec_lens[b] = max(1, min(total, LCAP));
  }
}

// ---------------------------------------------------------------------------
// Kernel 2: CTC on raw acts, LOG2 domain (round-5 math, absmax 0.0).
// Lane-major: lane holds R consecutive states in registers; 2 edge shuffles
// per step (issued at step end for the next step). Row logits loaded
// COALESCED (2 floats/lane) into named register pairs (4-deep rotation, no
// arrays-by-pointer -> no scratch), distributed to states via __shfl
// (2 bpermutes + select per state; consumed only at the final FMA).
// Ghost-zone refresh via LDS every HREF=30 steps (front 2/step < 63 ghost).
// ---------------------------------------------------------------------------
__device__ __forceinline__ float lse3f(float a0, float a1, float a2) {
  float m = fmaxf(fmaxf(a0, a1), a2);
  float sm = __builtin_exp2f(a0 - m) + __builtin_exp2f(a1 - m) +
             __builtin_exp2f(a2 - m);
  return m + __builtin_log2f(sm);
}

template <int R>
__device__ __forceinline__ void ctc_core(
    const float* __restrict__ act_b, const int* __restrict__ lab, int Tl,
    int len, int S, float* __restrict__ xall, float* __restrict__ fin,
    float* __restrict__ ends, int outIdx) {
  const int tid = threadIdx.x;
  const int lane = tid & 63, wv = tid >> 6;
  const int lm1 = (lane + 63) & 63;
  const int oS = (S + 3) >> 2;     // owned span per wave
  const int o0 = min(wv * oS, S);
  const int o1 = min(o0 + oS, S);
  const int p0 = max(0, o0 - 63);  // processed bottom (63-state ghost)

  float alpha[R];
  int exlo[R];
  bool al2[R], hsel[R];
#pragma unroll
  for (int r = 0; r < R; r++) {
    int s = p0 + lane * R + r;
    alpha[r] = NEGF;
    exlo[r] = 0;
    al2[r] = false;
    hsel[r] = false;
    if (s < S && (s & 1)) {
      int i = s >> 1;
      int e = lab[i];
      exlo[r] = e & 63;
      hsel[r] = e >= 64;
      al2[r] = (s >= 3) && (e != 0) && (e != lab[i - 1]);
    }
  }
  // t=0 init: states 0,1 live in wave 0, lane 0 (R >= 2 always)
  if (wv == 0 && lane == 0) {
    alpha[0] = act_b[0] * L2E;
    int e1 = exlo[1] + (hsel[1] ? 64 : 0);
    alpha[1] = act_b[e1] * L2E;
  }
  float pT1 = __shfl(alpha[R - 1], lm1);
  float pT2 = __shfl(alpha[R - 2], lm1);

  float cA0, cA1, cB0, cB1, cC0, cC1, cD0, cD1;

#define PREF(C0v, C1v, ROW)                                \
  {                                                        \
    const float* rp_ = act_b + (size_t)(ROW) * (BB * VV);  \
    C0v = rp_[lane];                                       \
    C1v = rp_[lane + 64];                                  \
  }

#define STEPK(C0v, C1v)                                                    \
  {                                                                        \
    float Gv[R];                                                           \
    _Pragma("unroll") for (int r = 0; r < R; r++) {                        \
      float lo_ = __shfl(C0v, exlo[r]);                                    \
      float hi_ = __shfl(C1v, exlo[r]);                                    \
      Gv[r] = hsel[r] ? hi_ : lo_;                                         \
    }                                                                      \
    float pe1 = (lane != 0) ? pT1 : NEGF;                                  \
    float pe2 = (lane != 0) ? pT2 : NEGF;                                  \
    _Pragma("unroll") for (int r = R - 1; r >= 2; r--) {                   \
      float a2_ = al2[r] ? alpha[r - 2] : NEGF;                            \
      alpha[r] =                                                           \
          __builtin_fmaf(Gv[r], L2E, lse3f(alpha[r], alpha[r - 1], a2_));  \
    }                                                                      \
    {                                                                      \
      float a2_ = al2[1] ? pe1 : NEGF;                                     \
      alpha[1] = __builtin_fmaf(Gv[1], L2E, lse3f(alpha[1], alpha[0], a2_)); \
    }                                                                      \
    {                                                                      \
      float a2_ = al2[0] ? pe2 : NEGF;                                     \
      alpha[0] = __builtin_fmaf(Gv[0], L2E, lse3f(alpha[0], pe1, a2_));    \
    }                                                                      \
    pT1 = __shfl(alpha[R - 1], lm1);                                       \
    pT2 = __shfl(alpha[R - 2], lm1);                                       \
  }

#define REFRESH()                                      \
  {                                                    \
    __syncthreads();                                   \
    _Pragma("unroll") for (int r = 0; r < R; r++) {    \
      int s_ = p0 + lane * R + r;                      \
      if (s_ >= o0 && s_ < o1) xall[s_] = alpha[r];    \
    }                                                  \
    __syncthreads();                                   \
    _Pragma("unroll") for (int r = 0; r < R; r++) {    \
      int s_ = p0 + lane * R + r;                      \
      if (s_ < o0) alpha[r] = xall[s_];                \
    }                                                  \
    pT1 = __shfl(alpha[R - 1], lm1);                   \
    pT2 = __shfl(alpha[R - 2], lm1);                   \
  }

#define STAGE(P0, P1, U0, U1)          \
  PREF(P0, P1, min(t + 3, Tl - 1));    \
  STEPK(U0, U1);                       \
  ++t;                                 \
  if (++since >= HREF) {               \
    if (t < Tl) REFRESH();             \
    since = 0;                         \
  }                                    \
  if (t >= Tl) break;

  PREF(cB0, cB1, min(1, Tl - 1));
  PREF(cC0, cC1, min(2, Tl - 1));
  PREF(cD0, cD1, min(3, Tl - 1));

  int t = 1, since = 0;
  while (t < Tl) {
    STAGE(cA0, cA1, cB0, cB1)
    STAGE(cB0, cB1, cC0, cC1)
    STAGE(cC0, cC1, cD0, cD1)
    STAGE(cD0, cD1, cA0, cA1)
  }
#undef STAGE
#undef REFRESH
#undef STEPK
#undef PREF

  // end = logaddexp(alpha[2*len], alpha[2*len-1]) from owned states
  __syncthreads();
#pragma unroll
  for (int r = 0; r < R; r++) {
    int s = p0 + lane * R + r;
    if (s >= o0 && s < o1) {
      if (s == 2 * len) fin[0] = alpha[r];
      if (s == 2 * len - 1) fin[1] = alpha[r];
    }
  }
  __syncthreads();
  if (tid == 0) {
    float a = fin[0], c = fin[1];
    float m = fmaxf(a, c);
    float e = m + __builtin_log2f(__builtin_exp2f(a - m) + __builtin_exp2f(c - m));
    ends[outIdx] = e;
  }
}

__global__ __launch_bounds__(256, 1) void ctc_kernel(
    const float* __restrict__ acts, const int* __restrict__ labels_gt,
    const int* __restrict__ act_lens, const int* __restrict__ label_lens,
    const int* __restrict__ dec, const int* __restrict__ dec_lens,
    float* __restrict__ ends) {
  __shared__ float xall[2 * LCAP + 1];
  __shared__ float fin[2];
  const int b = blockIdx.x >> 1;
  const int hyp = blockIdx.x & 1;
  const int Tl = act_lens[b];
  const int len = hyp ? dec_lens[b] : label_lens[b];
  const int* lab = hyp ? (dec + (size_t)b * LCAP) : (labels_gt + (size_t)b * LGT);
  const int S = 2 * len + 1;
  const float* act_b = acts + (size_t)b * VV;  // acts[(t*BB + b)*VV + v]
  const int oS = (S + 3) >> 2;
  int Rd = (oS + 126) >> 6;  // ceil((oS+63)/64)
  if (Rd < 2) Rd = 2;
  const int oi = hyp * BB + b;
  if (Rd == 2)
    ctc_core<2>(act_b, lab, Tl, len, S, xall, fin, ends, oi);
  else if (Rd == 3)
    ctc_core<3>(act_b, lab, Tl, len, S, xall, fin, ends, oi);
  else if (Rd == 4)
    ctc_core<4>(act_b, lab, Tl, len, S, xall, fin, ends, oi);
  else
    ctc_core<5>(act_b, lab, Tl, len, S, xall, fin, ends, oi);
}

// ---------------------------------------------------------------------------
// Kernel 3: out[b] = (end_hyp' - end_gt') * ln2 + 1.0  (log2-domain ends)
// ---------------------------------------------------------------------------
__global__ void final_kernel(const float* __restrict__ ends,
                             float* __restrict__ out) {
  int b = threadIdx.x;
  if (b < BB) out[b] = (ends[BB + b] - ends[b]) * LN2F + 1.0f;
}

extern "C" void kernel_launch(void* const* d_in, const int* in_sizes, int n_in,
                              void* d_out, int out_size, void* d_ws,
                              size_t ws_size, hipStream_t stream) {
  const float* acts = (const float*)d_in[0];
  const int* labels = (const int*)d_in[1];
  const int* act_lens = (const int*)d_in[2];
  const int* label_lens = (const int*)d_in[3];
  float* out = (float*)d_out;

  char* ws = (char*)d_ws;
  int* dec = (int*)ws;                                          // B*LCAP ints
  int* dec_lens = (int*)(ws + (size_t)BB * LCAP * 4);           // B ints
  float* ends = (float*)(ws + (size_t)BB * LCAP * 4 + BB * 4);  // 2*B floats

  decode_kernel<<<dim3(BB), dim3(256), 0, stream>>>(acts, act_lens, dec, dec_lens);
  ctc_kernel<<<dim3(2 * BB), dim3(256), 0, stream>>>(acts, labels, act_lens,
                                                     label_lens, dec, dec_lens, ends);
  final_kernel<<<dim3(1), dim3(128), 0, stream>>>(ends, out);
}

// Round 8
// 732.603 us; speedup vs baseline: 1.0976x; 1.0976x over previous
//
#include <hip/hip_runtime.h>

#define TT 1500
#define BB 96
#define VV 128
#define LGT 256
#define LCAP 512
#define NEGF (-1.0e30f)
#define L2E 1.4426950408889634f
#define LN2F 0.6931471805599453f
#define HREF 30  // refresh cadence: 2*HREF=60 < 63-state ghost

// ---------------------------------------------------------------------------
// Kernel 1: greedy decode (unchanged).
// ---------------------------------------------------------------------------
__global__ __launch_bounds__(256) void decode_kernel(
    const float* __restrict__ acts, const int* __restrict__ act_lens,
    int* __restrict__ dec, int* __restrict__ dec_lens) {
  __shared__ int preds[TT];
  __shared__ int sc[256];
  const int b = blockIdx.x;
  const int tid = threadIdx.x;
  const int Tl = act_lens[b];
  for (int t = tid; t < Tl; t += 256) {
    const float4* r4 = (const float4*)(acts + ((size_t)t * BB + b) * VV);
    float best = -3.4e38f;
    int bi = 0;
#pragma unroll
    for (int i = 0; i < VV / 4; i++) {
      float4 v = r4[i];
      if (v.x > best) { best = v.x; bi = 4 * i; }
      if (v.y > best) { best = v.y; bi = 4 * i + 1; }
      if (v.z > best) { best = v.z; bi = 4 * i + 2; }
      if (v.w > best) { best = v.w; bi = 4 * i + 3; }
    }
    preds[t] = bi;
  }
  __syncthreads();

  int pv[6];
  bool fl[6];
  int cnt = 0;
#pragma unroll
  for (int j = 0; j < 6; j++) {
    int t = tid * 6 + j;
    bool valid = t < Tl;
    int p = valid ? preds[t] : 0;
    int pr = (t == 0) ? -1 : (valid ? preds[t - 1] : -1);
    bool f = valid && (p != 0) && (p != pr);
    pv[j] = p;
    fl[j] = f;
    cnt += f;
  }
  sc[tid] = cnt;
  __syncthreads();
  for (int off = 1; off < 256; off <<= 1) {
    int v = sc[tid];
    if (tid >= off) v += sc[tid - off];
    __syncthreads();
    sc[tid] = v;
    __syncthreads();
  }
  int pos = sc[tid] - cnt;  // exclusive prefix
  int total = sc[255];
  int* db = dec + (size_t)b * LCAP;
#pragma unroll
  for (int j = 0; j < 6; j++) {
    if (fl[j]) {
      if (pos < LCAP) db[pos] = pv[j];
      pos++;
    }
  }
  if (tid == 0) {
    if (total == 0) db[0] = 0;
    dec_lens[b] = max(1, min(total, LCAP));
  }
}

// ---------------------------------------------------------------------------
// Kernel 2: CTC on raw acts, LOG2 domain. Lane-major: lane holds R
// consecutive states in registers; 2 edge bpermutes per step (issued at step
// end for the next step). Per-state logits gathered DIRECTLY from global
// (addresses within one 512B row -> ~4 cachelines/load), 3 rows ahead via a
// 4-buffer rotation of plain unrolled register arrays (macros, no lambdas,
// no pointer escape -> no scratch). Ghost refresh via LDS every HREF steps.
// ---------------------------------------------------------------------------
__device__ __forceinline__ float lse3f(float a0, float a1, float a2) {
  float m = fmaxf(fmaxf(a0, a1), a2);
  float sm = __builtin_exp2f(a0 - m) + __builtin_exp2f(a1 - m) +
             __builtin_exp2f(a2 - m);
  return m + __builtin_log2f(sm);
}

template <int R>
__device__ __forceinline__ void ctc_core(
    const float* __restrict__ act_b, const int* __restrict__ lab, int Tl,
    int len, int S, float* __restrict__ xall, float* __restrict__ fin,
    float* __restrict__ ends, int outIdx) {
  const int tid = threadIdx.x;
  const int lane = tid & 63, wv = tid >> 6;
  const int lm1 = (lane + 63) & 63;
  const int oS = (S + 3) >> 2;     // owned span per wave
  const int o0 = min(wv * oS, S);
  const int o1 = min(o0 + oS, S);
  const int p0 = max(0, o0 - 63);  // processed bottom (63-state ghost)

  float alpha[R];
  float gA[R], gB[R], gC[R], gD[R];
  int extk[R];
  bool al2[R];
#pragma unroll
  for (int r = 0; r < R; r++) {
    int s = p0 + lane * R + r;
    alpha[r] = NEGF;
    extk[r] = 0;
    al2[r] = false;
    if (s < S && (s & 1)) {
      int i = s >> 1;
      int e = lab[i];
      extk[r] = e;
      al2[r] = (s >= 3) && (e != 0) && (e != lab[i - 1]);
    }
  }
  // t=0 init: states 0,1 live in wave 0, lane 0 (R >= 2 always)
  if (wv == 0 && lane == 0) {
    alpha[0] = act_b[0] * L2E;
    alpha[1] = act_b[extk[1]] * L2E;
  }
  float pT1 = __shfl(alpha[R - 1], lm1);
  float pT2 = __shfl(alpha[R - 2], lm1);

#define PREF(GN, ROW)                                      \
  {                                                        \
    const float* rp_ = act_b + (size_t)(ROW) * (BB * VV);  \
    _Pragma("unroll") for (int r = 0; r < R; r++)          \
        GN[r] = rp_[extk[r]];                              \
  }

#define STEPK(GN)                                                          \
  {                                                                        \
    float pe1 = (lane != 0) ? pT1 : NEGF;                                  \
    float pe2 = (lane != 0) ? pT2 : NEGF;                                  \
    _Pragma("unroll") for (int r = R - 1; r >= 2; r--) {                   \
      float a2_ = al2[r] ? alpha[r - 2] : NEGF;                            \
      alpha[r] =                                                           \
          __builtin_fmaf(GN[r], L2E, lse3f(alpha[r], alpha[r - 1], a2_));  \
    }                                                                      \
    {                                                                      \
      float a2_ = al2[1] ? pe1 : NEGF;                                     \
      alpha[1] = __builtin_fmaf(GN[1], L2E, lse3f(alpha[1], alpha[0], a2_)); \
    }                                                                      \
    {                                                                      \
      float a2_ = al2[0] ? pe2 : NEGF;                                     \
      alpha[0] = __builtin_fmaf(GN[0], L2E, lse3f(alpha[0], pe1, a2_));    \
    }                                                                      \
    pT1 = __shfl(alpha[R - 1], lm1);                                       \
    pT2 = __shfl(alpha[R - 2], lm1);                                       \
  }

#define REFRESH()                                      \
  {                                                    \
    __syncthreads();                                   \
    _Pragma("unroll") for (int r = 0; r < R; r++) {    \
      int s_ = p0 + lane * R + r;                      \
      if (s_ >= o0 && s_ < o1) xall[s_] = alpha[r];    \
    }                                                  \
    __syncthreads();                                   \
    _Pragma("unroll") for (int r = 0; r < R; r++) {    \
      int s_ = p0 + lane * R + r;                      \
      if (s_ < o0) alpha[r] = xall[s_];                \
    }                                                  \
    pT1 = __shfl(alpha[R - 1], lm1);                   \
    pT2 = __shfl(alpha[R - 2], lm1);                   \
  }

#define STAGE(PG, UG)                  \
  PREF(PG, min(t + 3, Tl - 1));        \
  STEPK(UG);                           \
  ++t;                                 \
  if (++since >= HREF) {               \
    if (t < Tl) REFRESH();             \
    since = 0;                         \
  }                                    \
  if (t >= Tl) break;

  PREF(gB, min(1, Tl - 1));
  PREF(gC, min(2, Tl - 1));
  PREF(gD, min(3, Tl - 1));

  int t = 1, since = 0;
  while (t < Tl) {
    STAGE(gA, gB)
    STAGE(gB, gC)
    STAGE(gC, gD)
    STAGE(gD, gA)
  }
#undef STAGE
#undef REFRESH
#undef STEPK
#undef PREF

  // end = logaddexp(alpha[2*len], alpha[2*len-1]) from owned states
  __syncthreads();
#pragma unroll
  for (int r = 0; r < R; r++) {
    int s = p0 + lane * R + r;
    if (s >= o0 && s < o1) {
      if (s == 2 * len) fin[0] = alpha[r];
      if (s == 2 * len - 1) fin[1] = alpha[r];
    }
  }
  __syncthreads();
  if (tid == 0) {
    float a = fin[0], c = fin[1];
    float m = fmaxf(a, c);
    float e = m + __builtin_log2f(__builtin_exp2f(a - m) + __builtin_exp2f(c - m));
    ends[outIdx] = e;
  }
}

__global__ __launch_bounds__(256, 1) void ctc_kernel(
    const float* __restrict__ acts, const int* __restrict__ labels_gt,
    const int* __restrict__ act_lens, const int* __restrict__ label_lens,
    const int* __restrict__ dec, const int* __restrict__ dec_lens,
    float* __restrict__ ends) {
  __shared__ float xall[2 * LCAP + 1];
  __shared__ float fin[2];
  const int b = blockIdx.x >> 1;
  const int hyp = blockIdx.x & 1;
  const int Tl = act_lens[b];
  const int len = hyp ? dec_lens[b] : label_lens[b];
  const int* lab = hyp ? (dec + (size_t)b * LCAP) : (labels_gt + (size_t)b * LGT);
  const int S = 2 * len + 1;
  const float* act_b = acts + (size_t)b * VV;  // acts[(t*BB + b)*VV + v]
  const int oS = (S + 3) >> 2;
  int Rd = (oS + 126) >> 6;  // ceil((oS+63)/64)
  if (Rd < 2) Rd = 2;
  const int oi = hyp * BB + b;
  if (Rd == 2)
    ctc_core<2>(act_b, lab, Tl, len, S, xall, fin, ends, oi);
  else if (Rd == 3)
    ctc_core<3>(act_b, lab, Tl, len, S, xall, fin, ends, oi);
  else if (Rd == 4)
    ctc_core<4>(act_b, lab, Tl, len, S, xall, fin, ends, oi);
  else
    ctc_core<5>(act_b, lab, Tl, len, S, xall, fin, ends, oi);
}

// ---------------------------------------------------------------------------
// Kernel 3: out[b] = (end_hyp' - end_gt') * ln2 + 1.0  (log2-domain ends)
// ---------------------------------------------------------------------------
__global__ void final_kernel(const float* __restrict__ ends,
                             float* __restrict__ out) {
  int b = threadIdx.x;
  if (b < BB) out[b] = (ends[BB + b] - ends[b]) * LN2F + 1.0f;
}

extern "C" void kernel_launch(void* const* d_in, const int* in_sizes, int n_in,
                              void* d_out, int out_size, void* d_ws,
                              size_t ws_size, hipStream_t stream) {
  const float* acts = (const float*)d_in[0];
  const int* labels = (const int*)d_in[1];
  const int* act_lens = (const int*)d_in[2];
  const int* label_lens = (const int*)d_in[3];
  float* out = (float*)d_out;

  char* ws = (char*)d_ws;
  int* dec = (int*)ws;                                          // B*LCAP ints
  int* dec_lens = (int*)(ws + (size_t)BB * LCAP * 4);           // B ints
  float* ends = (float*)(ws + (size_t)BB * LCAP * 4 + BB * 4);  // 2*B floats

  decode_kernel<<<dim3(BB), dim3(256), 0, stream>>>(acts, act_lens, dec, dec_lens);
  ctc_kernel<<<dim3(2 * BB), dim3(256), 0, stream>>>(acts, labels, act_lens,
                                                     label_lens, dec, dec_lens, ends);
  final_kernel<<<dim3(1), dim3(128), 0, stream>>>(ends, out);
}